// Round 21
// baseline (327.271 us; speedup 1.0000x reference)
//
#include <hip/hip_runtime.h>

#define VN 5023
#define KN 8
#define BN 64
#define CIN 3
#define CH 64
#define MN 9
#define LAT 128
#define KTOT (VN*CH)      // 321472
#define NBV (BN*VN)       // 321472
#define KC 256
#define NCHUNK 1256       // KTOT/KC; last block: 192 = 6*32 valid k
#define RED_G 8
#define RED_J 157         // 1256 = 8*157
#define NXCD 8

// ------- kernel 1+2 FUSED: conv1 -> LDS h-tile -> encoder split-K ------------
// Block owns vertices 4*blk..+3 (= its K-chunk) x all 64 batches.
// Phase 1 (conv): wave = vertex (dst/aw wave-uniform -> s_load), lane = batch;
//   relu(h) written straight to htile[256][64] (64KB, 2-way banks = free).
// Phase 2 (enc): r13 compute loop; We staged via single 16KB buffer with
//   reg-prefetch (2 barriers/subtile). LDS 80KB -> 2 blocks/CU; phase-1
//   gather latency hidden by co-resident block's FMA phase.
__global__ __launch_bounds__(256, 2) void k_convenc(
    const float* __restrict__ x, const float* __restrict__ aw,
    const int* __restrict__ dst,
    const float* __restrict__ u_e, const float* __restrict__ c_e,
    const float* __restrict__ W_e, const float* __restrict__ b_e,
    const float* __restrict__ We, float* __restrict__ partial)
{
  __shared__ float wlds[32*128];      // 16 KB, subtile of We, [kk][l] linear
  __shared__ float htile[256*64];     // 64 KB, [kk][b]
  int t = threadIdx.x;
  int blk = blockIdx.x;
  int lane = t & 63;                  // batch b in phase 1
  int vl = __builtin_amdgcn_readfirstlane(t >> 6);   // wave-uniform 0..3
  int vg = blk*4 + vl;
  int kbase0 = blk*KC;

  // issue We subtile-0 prefetch first (overlaps conv compute)
  float4 wreg[4];
  {
    const float* wsrc = We + (size_t)kbase0*LAT;
#pragma unroll
    for (int q=0;q<4;q++) wreg[q] = *(const float4*)(wsrc + (q*256+t)*4);
  }

  // ---- phase 1: conv for (vg, b=lane) ----
  if (vg < VN){
    int e0 = vg*KN;
    int jj[KN]; float awv[KN];
#pragma unroll
    for (int k=0;k<KN;k++){ jj[k] = dst[e0+k]; awv[k] = aw[e0+k]; }  // s_load
    const float* xb = x + (size_t)lane*VN*CIN;
    float xj0[KN], xj1[KN], xj2[KN];
#pragma unroll
    for (int k=0;k<KN;k++){
      const float* xr = xb + (size_t)jj[k]*3;
      xj0[k]=xr[0]; xj1[k]=xr[1]; xj2[k]=xr[2];
    }
    __builtin_amdgcn_sched_barrier(0);   // gathers issued before Ti math
    float xi0 = xb[(size_t)vg*3+0], xi1 = xb[(size_t)vg*3+1],
          xi2 = xb[(size_t)vg*3+2];
    float Ti[MN];
#pragma unroll
    for (int m=0;m<MN;m++)
      Ti[m] = xi0*u_e[m] + xi1*u_e[MN+m] + xi2*u_e[2*MN+m] + c_e[m];
    float agg[27];
#pragma unroll
    for (int i=0;i<27;i++) agg[i]=0.f;
#pragma unroll
    for (int k=0;k<KN;k++){
      float lg[MN];
#pragma unroll
      for (int m=0;m<MN;m++)
        lg[m] = Ti[m] - (xj0[k]*u_e[m]+xj1[k]*u_e[MN+m]+xj2[k]*u_e[2*MN+m]);
      float mx = lg[0];
#pragma unroll
      for (int m=1;m<MN;m++) mx = fmaxf(mx, lg[m]);
      float ex[MN], s=0.f;
#pragma unroll
      for (int m=0;m<MN;m++){ ex[m] = __expf(lg[m]-mx); s += ex[m]; }
      float r = awv[k] / s;
#pragma unroll
      for (int m=0;m<MN;m++){
        float a = ex[m]*r;
        agg[m*3+0] += a*xj0[k]; agg[m*3+1] += a*xj1[k]; agg[m*3+2] += a*xj2[k];
      }
    }
    for (int cc=0; cc<4; cc++){
      float y[16];
#pragma unroll
      for (int c=0;c<16;c++) y[c] = b_e[cc*16+c];
#pragma unroll
      for (int mc=0; mc<27; mc++){
        float a = agg[mc];
#pragma unroll
        for (int c=0;c<16;c++) y[c] += a * W_e[mc*CH + cc*16 + c];
      }
#pragma unroll
      for (int c=0;c<16;c++)
        htile[(vl*64 + cc*16 + c)*64 + lane] = fmaxf(y[c], 0.f);
    }
  } else {
#pragma unroll
    for (int c=0;c<CH;c++) htile[(vl*64+c)*64 + lane] = 0.f;
  }

  // stage subtile 0 into wlds; barrier covers htile + wlds
#pragma unroll
  for (int q=0;q<4;q++) *(float4*)(&wlds[(q*256+t)*4]) = wreg[q];
  __syncthreads();

  // ---- phase 2: encoder compute (r13 pattern, z from htile) ----
  int lq = t & 15;                    // l = lq*4..+3 and 64+lq*4..+3
  int bq = t >> 4;                    // b = bq*4..+3
  float acc[8][4];
#pragma unroll
  for (int i=0;i<8;i++)
#pragma unroll
    for (int j=0;j<4;j++) acc[i][j]=0.f;
  int nt0 = (blk == NCHUNK-1) ? 6 : 8;

  for (int t0=0; t0<nt0; t0++){
    bool pf = (t0+1 < nt0);
    if (pf){
      const float* wsrc = We + (size_t)(kbase0 + (t0+1)*32)*LAT;
#pragma unroll
      for (int q=0;q<4;q++) wreg[q] = *(const float4*)(wsrc + (q*256+t)*4);
    }
    __builtin_amdgcn_sched_barrier(0);
#pragma unroll 4
    for (int kk=0; kk<32; kk++){
      float4 w0 = *(const float4*)(&wlds[kk*128 + lq*4]);
      float4 w1 = *(const float4*)(&wlds[kk*128 + 64 + lq*4]);
      float4 z  = *(const float4*)(&htile[(t0*32+kk)*64 + bq*4]);
      float wv[8] = {w0.x,w0.y,w0.z,w0.w,w1.x,w1.y,w1.z,w1.w};
      float zv[4] = {z.x,z.y,z.z,z.w};
#pragma unroll
      for (int li=0;li<8;li++)
#pragma unroll
        for (int bi=0;bi<4;bi++) acc[li][bi] += wv[li]*zv[bi];
    }
    __syncthreads();                  // wlds reads done
    if (pf){
#pragma unroll
      for (int q=0;q<4;q++) *(float4*)(&wlds[(q*256+t)*4]) = wreg[q];
      __syncthreads();                // wlds ready for next subtile
    }
  }
  float* pp = partial + (size_t)blk*(BN*LAT);
#pragma unroll
  for (int bi=0;bi<4;bi++){
    int b = bq*4+bi;
    float4 o0 = make_float4(acc[0][bi],acc[1][bi],acc[2][bi],acc[3][bi]);
    float4 o1 = make_float4(acc[4][bi],acc[5][bi],acc[6][bi],acc[7][bi]);
    *(float4*)(pp + b*LAT + lq*4)      = o0;
    *(float4*)(pp + b*LAT + 64 + lq*4) = o1;
  }
}

// ---------------- kernel 3a: coalesced partial reduce: 1256 -> 8 -------------
__global__ __launch_bounds__(256) void k_red1(
    const float* __restrict__ partial, float* __restrict__ partial2)
{
  int idx = blockIdx.x*256 + threadIdx.x;
  int g = blockIdx.y;
  float s = 0.f;
  for (int j=0;j<RED_J;j++)
    s += partial[(size_t)(g + RED_G*j)*(BN*LAT) + idx];
  partial2[(size_t)g*(BN*LAT) + idx] = s;
}

// ---------------- kernel 3b: 8 -> zT[l][b] + bias ----------------------------
__global__ __launch_bounds__(256) void k_red2(
    const float* __restrict__ partial2, const float* __restrict__ b_enc,
    float* __restrict__ zT)
{
  int idx = blockIdx.x*256 + threadIdx.x;
  float s = 0.f;
#pragma unroll
  for (int g=0; g<RED_G; g++) s += partial2[(size_t)g*(BN*LAT) + idx];
  int b = idx >> 7, l = idx & 127;
  zT[l*BN + b] = s + b_enc[l];
}

// ------- kernel 4: FUSED decoder + TG precompute (r16 epilogue, (256,8)) -----
__global__ __launch_bounds__(256, 8) void k_dectg(
    const float* __restrict__ zT, const float* __restrict__ Wd,
    const float* __restrict__ b_dec, const float* __restrict__ u_d,
    const float* __restrict__ W_d, float* __restrict__ TG)
{
  __shared__ float4 dt4[4][512];      // 32 KB, per-wave 8KB swizzled slab
  int t = threadIdx.x;
  int lane = t & 63;
  int wv = __builtin_amdgcn_readfirstlane(t >> 6);   // wave-uniform 0..3
  int blk = blockIdx.x;
  int vc = blk*256 + lane*4;
  int vs = vc < (KTOT-4) ? vc : (KTOT-4);            // clamped load address
  const float* wp = Wd + vs;
  const float* zrow = zT + wv*16;                    // + l*BN, wave-uniform
  float acc[4][16];
#pragma unroll
  for (int i=0;i<4;i++)
#pragma unroll
    for (int j=0;j<16;j++) acc[i][j]=0.f;

  float4 wA[4], wB[4];
#pragma unroll
  for (int u=0;u<4;u++) wA[u] = *(const float4*)(wp + (size_t)u*KTOT);

  for (int l0=0; l0<LAT; l0+=8){
#pragma unroll
    for (int u=0;u<4;u++) wB[u] = *(const float4*)(wp + (size_t)(l0+4+u)*KTOT);
    __builtin_amdgcn_sched_barrier(0);
#pragma unroll
    for (int u=0;u<4;u++){
      int l = l0+u;
      float zv[16];
#pragma unroll
      for (int j=0;j<16;j++) zv[j] = zrow[l*BN + j];   // uniform -> s_load
      float wvv[4] = {wA[u].x,wA[u].y,wA[u].z,wA[u].w};
#pragma unroll
      for (int i=0;i<4;i++)
#pragma unroll
        for (int j=0;j<16;j++) acc[i][j] += wvv[i]*zv[j];
    }
    if (l0+8 < LAT){
#pragma unroll
      for (int u=0;u<4;u++) wA[u] = *(const float4*)(wp + (size_t)(l0+8+u)*KTOT);
    }
    __builtin_amdgcn_sched_barrier(0);
#pragma unroll
    for (int u=0;u<4;u++){
      int l = l0+4+u;
      float zv[16];
#pragma unroll
      for (int j=0;j<16;j++) zv[j] = zrow[l*BN + j];
      float wvv[4] = {wB[u].x,wB[u].y,wB[u].z,wB[u].w};
#pragma unroll
      for (int i=0;i<4;i++)
#pragma unroll
        for (int j=0;j<16;j++) acc[i][j] += wvv[i]*zv[j];
    }
  }
  // bias; clamped-bias garbage only lands in masked (vg >= VN) pairs
  float4 bd = *(const float4*)(b_dec + vs);
  float bdv[4] = {bd.x, bd.y, bd.z, bd.w};
  int chb = lane & 15;                 // lane's ch-block within its vertex
  int vl4 = lane >> 4;                 // lane's vertex (0..3)

#pragma unroll
  for (int hh=0; hh<2; hh++){
#pragma unroll
    for (int jj=0; jj<8; jj++){
      int j = hh*8 + jj;
      dt4[wv][vl4*128 + jj*16 + (chb^jj)] =
        make_float4(acc[0][j]+bdv[0], acc[1][j]+bdv[1],
                    acc[2][j]+bdv[2], acc[3][j]+bdv[3]);
    }
    __syncthreads();
    if (lane < 32){
      int vl = lane >> 3, bl = lane & 7;
      int vg = blk*4 + vl;
      if (vg < VN){
        float Tg[36];
#pragma unroll
        for (int q=0;q<36;q++) Tg[q]=0.f;
#pragma unroll 1
        for (int cb=0; cb<16; cb++){
          float4 dq = dt4[wv][vl*128 + bl*16 + (cb^bl)];
          float dv4[4] = {dq.x,dq.y,dq.z,dq.w};
#pragma unroll
          for (int ii=0; ii<4; ii++){
            int c = cb*4 + ii;
            float dv = dv4[ii];
            const float* ur = u_d + c*MN;              // uniform -> s_load
#pragma unroll
            for (int m=0;m<MN;m++) Tg[m] += dv*ur[m];
#pragma unroll
            for (int m=0;m<MN;m++){
              const float* wr = W_d + (m*CH + c)*3;    // uniform -> s_load
              Tg[9+m*3+0] += dv*wr[0];
              Tg[9+m*3+1] += dv*wr[1];
              Tg[9+m*3+2] += dv*wr[2];
            }
          }
        }
        int bg = wv*16 + hh*8 + bl;
        float* tg = TG + (size_t)((size_t)bg*VN + vg)*36;
#pragma unroll
        for (int q=0;q<9;q++)
          *(float4*)(tg + q*4) = make_float4(Tg[q*4+0],Tg[q*4+1],
                                             Tg[q*4+2],Tg[q*4+3]);
      }
    }
    __syncthreads();
  }
}

// ---------------- kernel 6: attention + output -------------------------------
__global__ __launch_bounds__(256, 4) void k_att(
    const float* __restrict__ TG, const float* __restrict__ aw,
    const int* __restrict__ dst, const float* __restrict__ c_d,
    const float* __restrict__ b_d, float* __restrict__ out)
{
  int wg = blockIdx.x;
  int wgid = (wg & 7)*157 + (wg >> 3);    // chunk per XCD
  int t = wgid*256 + threadIdx.x;
  if (t >= NBV) return;
  int b = t / VN, v = t - b*VN;
  const float* TGb = TG + (size_t)b*VN*36;
  int e0 = v*KN;
  int4 j01 = *(const int4*)(dst + e0);
  int4 j23 = *(const int4*)(dst + e0 + 4);
  int jj[8] = {j01.x,j01.y,j01.z,j01.w, j23.x,j23.y,j23.z,j23.w};
  float4 a01 = *(const float4*)(aw + e0);
  float4 a23 = *(const float4*)(aw + e0 + 4);
  float awv[8] = {a01.x,a01.y,a01.z,a01.w, a23.x,a23.y,a23.z,a23.w};
  float Ti[MN];
#pragma unroll
  for (int m=0;m<MN;m++) Ti[m] = TGb[(size_t)v*36+m] + c_d[m];
  float y0=0.f, y1=0.f, y2=0.f;
  float4 q[9];
  {
    const float* Rp = TGb + (size_t)jj[0]*36;
#pragma unroll
    for (int i=0;i<9;i++) q[i] = *(const float4*)(Rp + i*4);
  }
#pragma unroll
  for (int k=0;k<KN;k++){
    float4 p[9];
    if (k+1 < KN){
      const float* Rp = TGb + (size_t)jj[k+1]*36;
#pragma unroll
      for (int i=0;i<9;i++) p[i] = *(const float4*)(Rp + i*4);
    }
    float rr[36] = {q[0].x,q[0].y,q[0].z,q[0].w, q[1].x,q[1].y,q[1].z,q[1].w,
                    q[2].x,q[2].y,q[2].z,q[2].w, q[3].x,q[3].y,q[3].z,q[3].w,
                    q[4].x,q[4].y,q[4].z,q[4].w, q[5].x,q[5].y,q[5].z,q[5].w,
                    q[6].x,q[6].y,q[6].z,q[6].w, q[7].x,q[7].y,q[7].z,q[7].w,
                    q[8].x,q[8].y,q[8].z,q[8].w};
    float lg[MN];
#pragma unroll
    for (int m=0;m<MN;m++) lg[m] = Ti[m] - rr[m];
    float mx = lg[0];
#pragma unroll
    for (int m=1;m<MN;m++) mx = fmaxf(mx, lg[m]);
    float ex[MN], s=0.f;
#pragma unroll
    for (int m=0;m<MN;m++){ ex[m] = __expf(lg[m]-mx); s += ex[m]; }
    float sc = awv[k] / s;
#pragma unroll
    for (int m=0;m<MN;m++){
      float a = ex[m]*sc;
      y0 += a*rr[9+m*3+0]; y1 += a*rr[9+m*3+1]; y2 += a*rr[9+m*3+2];
    }
    if (k+1 < KN){
#pragma unroll
      for (int i=0;i<9;i++) q[i] = p[i];
    }
  }
  float* o = out + (size_t)t*3;
  o[0]=fmaxf(y0+b_d[0],0.f); o[1]=fmaxf(y1+b_d[1],0.f); o[2]=fmaxf(y2+b_d[2],0.f);
}

extern "C" void kernel_launch(void* const* d_in, const int* in_sizes, int n_in,
                              void* d_out, int out_size, void* d_ws, size_t ws_size,
                              hipStream_t stream) {
  const float* x     = (const float*)d_in[0];
  const float* aw    = (const float*)d_in[1];
  const float* u_e   = (const float*)d_in[2];
  const float* c_e   = (const float*)d_in[3];
  const float* W_e   = (const float*)d_in[4];
  const float* b_e   = (const float*)d_in[5];
  const float* W_enc = (const float*)d_in[6];
  const float* b_enc = (const float*)d_in[7];
  const float* W_dec = (const float*)d_in[8];
  const float* b_dec = (const float*)d_in[9];
  const float* u_d   = (const float*)d_in[10];
  const float* c_d   = (const float*)d_in[11];
  const float* W_d   = (const float*)d_in[12];
  const float* b_d   = (const float*)d_in[13];
  const int*   dst   = (const int*)d_in[15];
  float* out = (float*)d_out;

  char* ws = (char*)d_ws;
  // Timeline/aliasing (h buffer ELIMINATED by conv+enc fusion):
  //   zT [0,32KB) + partial2 [64KB,320KB): low zone, written after convenc.
  //   partial [off1, +41.2MB): live convenc -> red1.
  //   TGbuf   [off1, +46.3MB): written by k_dectg (partial dead), read by att.
  float* zT   = (float*)ws;                               // 32 KB
  float* partial2 = (float*)(ws + (64<<10));              // 256 KB
  size_t off1 = (size_t)NBV*CH*sizeof(float);
  float* partial = (float*)(ws + off1);                   // 41.2 MB
  float* TGbuf   = (float*)(ws + off1);                   // 46.3 MB

  int grid_bv = (NBV + 255)/256;   // 1256

  k_convenc<<<NCHUNK,256,0,stream>>>(x, aw, dst, u_e, c_e, W_e, b_e,
                                     W_enc, partial);
  dim3 gr1(32, RED_G);
  k_red1<<<gr1,256,0,stream>>>(partial, partial2);
  k_red2<<<32,256,0,stream>>>(partial2, b_enc, zT);
  int grid_dec = (KTOT + 255)/256;   // 1256
  k_dectg<<<grid_dec,256,0,stream>>>(zT, W_dec, b_dec, u_d, W_d, TGbuf);
  k_att<<<grid_bv,256,0,stream>>>(TGbuf, aw, dst, c_d, b_d, out);
}

// Round 22
// 309.836 us; speedup vs baseline: 1.0563x; 1.0563x over previous
//
#include <hip/hip_runtime.h>

#define VN 5023
#define KN 8
#define BN 64
#define CIN 3
#define CH 64
#define MN 9
#define LAT 128
#define KTOT (VN*CH)      // 321472
#define NBV (BN*VN)       // 321472
#define KC 256
#define NCHUNK 1256       // KTOT/KC; last chunk 192 = 6*32 valid k
#define RED_G 8
#define RED_J 157         // 1256 = 8*157
#define NXCD 8

// ---------------- kernel 1: conv1 (x[B,V,3] -> h[B,V,64], relu) --------------
__global__ __launch_bounds__(256, 4) void k_conv1(
    const float* __restrict__ x, const float* __restrict__ aw,
    const int* __restrict__ dst,
    const float* __restrict__ u_e, const float* __restrict__ c_e,
    const float* __restrict__ W_e, const float* __restrict__ b_e,
    float* __restrict__ h)
{
  int t = blockIdx.x*256 + threadIdx.x;
  if (t >= NBV) return;
  int b = t / VN, v = t - b*VN;
  const float* xb = x + (size_t)b*VN*CIN;
  int e0 = v*KN;
  int4 j01 = *(const int4*)(dst + e0);
  int4 j23 = *(const int4*)(dst + e0 + 4);
  int jj[8] = {j01.x,j01.y,j01.z,j01.w, j23.x,j23.y,j23.z,j23.w};
  float4 a01 = *(const float4*)(aw + e0);
  float4 a23 = *(const float4*)(aw + e0 + 4);
  float awv[8] = {a01.x,a01.y,a01.z,a01.w, a23.x,a23.y,a23.z,a23.w};
  float xj0[8], xj1[8], xj2[8];
#pragma unroll
  for (int k=0;k<KN;k++){
    const float* xr = xb + (size_t)jj[k]*3;
    xj0[k]=xr[0]; xj1[k]=xr[1]; xj2[k]=xr[2];
  }
  __builtin_amdgcn_sched_barrier(0);
  float xi0 = xb[v*3+0], xi1 = xb[v*3+1], xi2 = xb[v*3+2];
  float Ti[MN];
#pragma unroll
  for (int m=0;m<MN;m++)
    Ti[m] = xi0*u_e[m] + xi1*u_e[MN+m] + xi2*u_e[2*MN+m] + c_e[m];
  float agg[27];
#pragma unroll
  for (int i=0;i<27;i++) agg[i]=0.f;
#pragma unroll
  for (int k=0;k<KN;k++){
    float lg[MN];
#pragma unroll
    for (int m=0;m<MN;m++)
      lg[m] = Ti[m] - (xj0[k]*u_e[m]+xj1[k]*u_e[MN+m]+xj2[k]*u_e[2*MN+m]);
    float mx = lg[0];
#pragma unroll
    for (int m=1;m<MN;m++) mx = fmaxf(mx, lg[m]);
    float ex[MN], s=0.f;
#pragma unroll
    for (int m=0;m<MN;m++){ ex[m] = __expf(lg[m]-mx); s += ex[m]; }
    float r = awv[k] / s;
#pragma unroll
    for (int m=0;m<MN;m++){
      float a = ex[m]*r;
      agg[m*3+0] += a*xj0[k]; agg[m*3+1] += a*xj1[k]; agg[m*3+2] += a*xj2[k];
    }
  }
  float* hr = h + (size_t)t*CH;
  for (int cc=0; cc<4; cc++){
    float y[16];
#pragma unroll
    for (int c=0;c<16;c++) y[c] = b_e[cc*16+c];
#pragma unroll
    for (int mc=0; mc<27; mc++){
      float a = agg[mc];
#pragma unroll
      for (int c=0;c<16;c++) y[c] += a * W_e[mc*CH + cc*16 + c];
    }
#pragma unroll
    for (int c=0;c<16;c+=4){
      float4 o = make_float4(fmaxf(y[c],0.f),fmaxf(y[c+1],0.f),
                             fmaxf(y[c+2],0.f),fmaxf(y[c+3],0.f));
      *(float4*)(hr + cc*16 + c) = o;
    }
  }
}

// ---------------- kernel 2: encoder split-K partials (r13, conflict-free) ----
__global__ __launch_bounds__(256, 4) void k_enc(
    const float* __restrict__ h, const float* __restrict__ We,
    float* __restrict__ partial)
{
  __shared__ float wlds[2][32*128];   // 2 x 16 KB, [kk][l] linear
  __shared__ float hlds[2][32][68];   // 2 x 8.7 KB, [kk][b] padded
  int t = threadIdx.x;
  int blk = blockIdx.x;
  int lq = t & 15;                    // l = lq*4..+3 and 64+lq*4..+3
  int bq = t >> 4;                    // b = bq*4..+3
  float acc[8][4];
#pragma unroll
  for (int i=0;i<8;i++)
#pragma unroll
    for (int j=0;j<4;j++) acc[i][j]=0.f;
  int kbase0 = blk*KC;
  int ldb = t & 63;
  int seg = t >> 6;
  int nt0 = (blk == NCHUNK-1) ? 6 : 8;

  float4 wreg0, wreg1, wreg2, wreg3, hreg0, hreg1;
  {
    const float* wsrc = We + (size_t)kbase0*LAT;
    wreg0 = *(const float4*)(wsrc + 0*1024 + t*4);
    wreg1 = *(const float4*)(wsrc + 1*1024 + t*4);
    wreg2 = *(const float4*)(wsrc + 2*1024 + t*4);
    wreg3 = *(const float4*)(wsrc + 3*1024 + t*4);
    const float* hsrc = h + (size_t)ldb*KTOT + kbase0 + seg*8;
    hreg0 = *(const float4*)(hsrc);
    hreg1 = *(const float4*)(hsrc + 4);
    *(float4*)(&wlds[0][0*1024 + t*4]) = wreg0;
    *(float4*)(&wlds[0][1*1024 + t*4]) = wreg1;
    *(float4*)(&wlds[0][2*1024 + t*4]) = wreg2;
    *(float4*)(&wlds[0][3*1024 + t*4]) = wreg3;
    hlds[0][seg*8+0][ldb]=hreg0.x; hlds[0][seg*8+1][ldb]=hreg0.y;
    hlds[0][seg*8+2][ldb]=hreg0.z; hlds[0][seg*8+3][ldb]=hreg0.w;
    hlds[0][seg*8+4][ldb]=hreg1.x; hlds[0][seg*8+5][ldb]=hreg1.y;
    hlds[0][seg*8+6][ldb]=hreg1.z; hlds[0][seg*8+7][ldb]=hreg1.w;
  }
  __syncthreads();

  int cur = 0;
  for (int t0=0; t0<nt0; t0++){
    bool pf = (t0+1 < nt0);
    if (pf){
      int kbase = kbase0 + (t0+1)*32;
      const float* wsrc = We + (size_t)kbase*LAT;
      wreg0 = *(const float4*)(wsrc + 0*1024 + t*4);
      wreg1 = *(const float4*)(wsrc + 1*1024 + t*4);
      wreg2 = *(const float4*)(wsrc + 2*1024 + t*4);
      wreg3 = *(const float4*)(wsrc + 3*1024 + t*4);
      const float* hsrc = h + (size_t)ldb*KTOT + kbase + seg*8;
      hreg0 = *(const float4*)(hsrc);
      hreg1 = *(const float4*)(hsrc + 4);
    }
    __builtin_amdgcn_sched_barrier(0);
#pragma unroll 4
    for (int kk=0; kk<32; kk++){
      float4 w0 = *(const float4*)(&wlds[cur][kk*128 + lq*4]);
      float4 w1 = *(const float4*)(&wlds[cur][kk*128 + 64 + lq*4]);
      float4 z  = *(const float4*)(&hlds[cur][kk][bq*4]);
      float wv[8] = {w0.x,w0.y,w0.z,w0.w,w1.x,w1.y,w1.z,w1.w};
      float zv[4] = {z.x,z.y,z.z,z.w};
#pragma unroll
      for (int li=0;li<8;li++)
#pragma unroll
        for (int bi=0;bi<4;bi++) acc[li][bi] += wv[li]*zv[bi];
    }
    if (pf){
      int nb = cur^1;
      *(float4*)(&wlds[nb][0*1024 + t*4]) = wreg0;
      *(float4*)(&wlds[nb][1*1024 + t*4]) = wreg1;
      *(float4*)(&wlds[nb][2*1024 + t*4]) = wreg2;
      *(float4*)(&wlds[nb][3*1024 + t*4]) = wreg3;
      hlds[nb][seg*8+0][ldb]=hreg0.x; hlds[nb][seg*8+1][ldb]=hreg0.y;
      hlds[nb][seg*8+2][ldb]=hreg0.z; hlds[nb][seg*8+3][ldb]=hreg0.w;
      hlds[nb][seg*8+4][ldb]=hreg1.x; hlds[nb][seg*8+5][ldb]=hreg1.y;
      hlds[nb][seg*8+6][ldb]=hreg1.z; hlds[nb][seg*8+7][ldb]=hreg1.w;
    }
    __syncthreads();
    cur ^= 1;
  }
  float* pp = partial + (size_t)blk*(BN*LAT);
#pragma unroll
  for (int bi=0;bi<4;bi++){
    int b = bq*4+bi;
    float4 o0 = make_float4(acc[0][bi],acc[1][bi],acc[2][bi],acc[3][bi]);
    float4 o1 = make_float4(acc[4][bi],acc[5][bi],acc[6][bi],acc[7][bi]);
    *(float4*)(pp + b*LAT + lq*4)      = o0;
    *(float4*)(pp + b*LAT + 64 + lq*4) = o1;
  }
}

// ---------------- kernel 3a: coalesced partial reduce: 1256 -> 8 -------------
__global__ __launch_bounds__(256) void k_red1(
    const float* __restrict__ partial, float* __restrict__ partial2)
{
  int idx = blockIdx.x*256 + threadIdx.x;
  int g = blockIdx.y;
  float s = 0.f;
  for (int j=0;j<RED_J;j++)
    s += partial[(size_t)(g + RED_G*j)*(BN*LAT) + idx];
  partial2[(size_t)g*(BN*LAT) + idx] = s;
}

// ---------------- kernel 3b: 8 -> zT[l][b] + bias ----------------------------
__global__ __launch_bounds__(256) void k_red2(
    const float* __restrict__ partial2, const float* __restrict__ b_enc,
    float* __restrict__ zT)
{
  int idx = blockIdx.x*256 + threadIdx.x;
  float s = 0.f;
#pragma unroll
  for (int g=0; g<RED_G; g++) s += partial2[(size_t)g*(BN*LAT) + idx];
  int b = idx >> 7, l = idx & 127;
  zT[l*BN + b] = s + b_enc[l];
}

// ------- kernel 4: FUSED decoder + TG precompute (r16 epilogue, (256,8)) -----
__global__ __launch_bounds__(256, 8) void k_dectg(
    const float* __restrict__ zT, const float* __restrict__ Wd,
    const float* __restrict__ b_dec, const float* __restrict__ u_d,
    const float* __restrict__ W_d, float* __restrict__ TG)
{
  __shared__ float4 dt4[4][512];      // 32 KB, per-wave 8KB swizzled slab
  int t = threadIdx.x;
  int lane = t & 63;
  int wv = __builtin_amdgcn_readfirstlane(t >> 6);   // wave-uniform 0..3
  int blk = blockIdx.x;
  int vc = blk*256 + lane*4;
  int vs = vc < (KTOT-4) ? vc : (KTOT-4);            // clamped load address
  const float* wp = Wd + vs;
  const float* zrow = zT + wv*16;                    // + l*BN, wave-uniform
  float acc[4][16];
#pragma unroll
  for (int i=0;i<4;i++)
#pragma unroll
    for (int j=0;j<16;j++) acc[i][j]=0.f;

  float4 wA[4], wB[4];
#pragma unroll
  for (int u=0;u<4;u++) wA[u] = *(const float4*)(wp + (size_t)u*KTOT);

  for (int l0=0; l0<LAT; l0+=8){
#pragma unroll
    for (int u=0;u<4;u++) wB[u] = *(const float4*)(wp + (size_t)(l0+4+u)*KTOT);
    __builtin_amdgcn_sched_barrier(0);
#pragma unroll
    for (int u=0;u<4;u++){
      int l = l0+u;
      float zv[16];
#pragma unroll
      for (int j=0;j<16;j++) zv[j] = zrow[l*BN + j];   // uniform -> s_load
      float wvv[4] = {wA[u].x,wA[u].y,wA[u].z,wA[u].w};
#pragma unroll
      for (int i=0;i<4;i++)
#pragma unroll
        for (int j=0;j<16;j++) acc[i][j] += wvv[i]*zv[j];
    }
    if (l0+8 < LAT){
#pragma unroll
      for (int u=0;u<4;u++) wA[u] = *(const float4*)(wp + (size_t)(l0+8+u)*KTOT);
    }
    __builtin_amdgcn_sched_barrier(0);
#pragma unroll
    for (int u=0;u<4;u++){
      int l = l0+4+u;
      float zv[16];
#pragma unroll
      for (int j=0;j<16;j++) zv[j] = zrow[l*BN + j];
      float wvv[4] = {wB[u].x,wB[u].y,wB[u].z,wB[u].w};
#pragma unroll
      for (int i=0;i<4;i++)
#pragma unroll
        for (int j=0;j<16;j++) acc[i][j] += wvv[i]*zv[j];
    }
  }
  // bias; clamped-bias garbage only lands in masked (vg >= VN) pairs
  float4 bd = *(const float4*)(b_dec + vs);
  float bdv[4] = {bd.x, bd.y, bd.z, bd.w};
  int chb = lane & 15;                 // lane's ch-block within its vertex
  int vl4 = lane >> 4;                 // lane's vertex (0..3)

#pragma unroll
  for (int hh=0; hh<2; hh++){
#pragma unroll
    for (int jj=0; jj<8; jj++){
      int j = hh*8 + jj;
      dt4[wv][vl4*128 + jj*16 + (chb^jj)] =
        make_float4(acc[0][j]+bdv[0], acc[1][j]+bdv[1],
                    acc[2][j]+bdv[2], acc[3][j]+bdv[3]);
    }
    __syncthreads();
    if (lane < 32){
      int vl = lane >> 3, bl = lane & 7;
      int vg = blk*4 + vl;
      if (vg < VN){
        float Tg[36];
#pragma unroll
        for (int q=0;q<36;q++) Tg[q]=0.f;
#pragma unroll 1
        for (int cb=0; cb<16; cb++){
          float4 dq = dt4[wv][vl*128 + bl*16 + (cb^bl)];
          float dv4[4] = {dq.x,dq.y,dq.z,dq.w};
#pragma unroll
          for (int ii=0; ii<4; ii++){
            int c = cb*4 + ii;
            float dv = dv4[ii];
            const float* ur = u_d + c*MN;              // uniform -> s_load
#pragma unroll
            for (int m=0;m<MN;m++) Tg[m] += dv*ur[m];
#pragma unroll
            for (int m=0;m<MN;m++){
              const float* wr = W_d + (m*CH + c)*3;    // uniform -> s_load
              Tg[9+m*3+0] += dv*wr[0];
              Tg[9+m*3+1] += dv*wr[1];
              Tg[9+m*3+2] += dv*wr[2];
            }
          }
        }
        int bg = wv*16 + hh*8 + bl;
        float* tg = TG + (size_t)((size_t)bg*VN + vg)*36;
#pragma unroll
        for (int q=0;q<9;q++)
          *(float4*)(tg + q*4) = make_float4(Tg[q*4+0],Tg[q*4+1],
                                             Tg[q*4+2],Tg[q*4+3]);
      }
    }
    __syncthreads();
  }
}

// ---------------- kernel 6: attention + output -------------------------------
__global__ __launch_bounds__(256, 4) void k_att(
    const float* __restrict__ TG, const float* __restrict__ aw,
    const int* __restrict__ dst, const float* __restrict__ c_d,
    const float* __restrict__ b_d, float* __restrict__ out)
{
  int wg = blockIdx.x;
  int wgid = (wg & 7)*157 + (wg >> 3);    // chunk per XCD
  int t = wgid*256 + threadIdx.x;
  if (t >= NBV) return;
  int b = t / VN, v = t - b*VN;
  const float* TGb = TG + (size_t)b*VN*36;
  int e0 = v*KN;
  int4 j01 = *(const int4*)(dst + e0);
  int4 j23 = *(const int4*)(dst + e0 + 4);
  int jj[8] = {j01.x,j01.y,j01.z,j01.w, j23.x,j23.y,j23.z,j23.w};
  float4 a01 = *(const float4*)(aw + e0);
  float4 a23 = *(const float4*)(aw + e0 + 4);
  float awv[8] = {a01.x,a01.y,a01.z,a01.w, a23.x,a23.y,a23.z,a23.w};
  float Ti[MN];
#pragma unroll
  for (int m=0;m<MN;m++) Ti[m] = TGb[(size_t)v*36+m] + c_d[m];
  float y0=0.f, y1=0.f, y2=0.f;
  float4 q[9];
  {
    const float* Rp = TGb + (size_t)jj[0]*36;
#pragma unroll
    for (int i=0;i<9;i++) q[i] = *(const float4*)(Rp + i*4);
  }
#pragma unroll
  for (int k=0;k<KN;k++){
    float4 p[9];
    if (k+1 < KN){
      const float* Rp = TGb + (size_t)jj[k+1]*36;
#pragma unroll
      for (int i=0;i<9;i++) p[i] = *(const float4*)(Rp + i*4);
    }
    float rr[36] = {q[0].x,q[0].y,q[0].z,q[0].w, q[1].x,q[1].y,q[1].z,q[1].w,
                    q[2].x,q[2].y,q[2].z,q[2].w, q[3].x,q[3].y,q[3].z,q[3].w,
                    q[4].x,q[4].y,q[4].z,q[4].w, q[5].x,q[5].y,q[5].z,q[5].w,
                    q[6].x,q[6].y,q[6].z,q[6].w, q[7].x,q[7].y,q[7].z,q[7].w,
                    q[8].x,q[8].y,q[8].z,q[8].w};
    float lg[MN];
#pragma unroll
    for (int m=0;m<MN;m++) lg[m] = Ti[m] - rr[m];
    float mx = lg[0];
#pragma unroll
    for (int m=1;m<MN;m++) mx = fmaxf(mx, lg[m]);
    float ex[MN], s=0.f;
#pragma unroll
    for (int m=0;m<MN;m++){ ex[m] = __expf(lg[m]-mx); s += ex[m]; }
    float sc = awv[k] / s;
#pragma unroll
    for (int m=0;m<MN;m++){
      float a = ex[m]*sc;
      y0 += a*rr[9+m*3+0]; y1 += a*rr[9+m*3+1]; y2 += a*rr[9+m*3+2];
    }
    if (k+1 < KN){
#pragma unroll
      for (int i=0;i<9;i++) q[i] = p[i];
    }
  }
  float* o = out + (size_t)t*3;
  o[0]=fmaxf(y0+b_d[0],0.f); o[1]=fmaxf(y1+b_d[1],0.f); o[2]=fmaxf(y2+b_d[2],0.f);
}

extern "C" void kernel_launch(void* const* d_in, const int* in_sizes, int n_in,
                              void* d_out, int out_size, void* d_ws, size_t ws_size,
                              hipStream_t stream) {
  const float* x     = (const float*)d_in[0];
  const float* aw    = (const float*)d_in[1];
  const float* u_e   = (const float*)d_in[2];
  const float* c_e   = (const float*)d_in[3];
  const float* W_e   = (const float*)d_in[4];
  const float* b_e   = (const float*)d_in[5];
  const float* W_enc = (const float*)d_in[6];
  const float* b_enc = (const float*)d_in[7];
  const float* W_dec = (const float*)d_in[8];
  const float* b_dec = (const float*)d_in[9];
  const float* u_d   = (const float*)d_in[10];
  const float* c_d   = (const float*)d_in[11];
  const float* W_d   = (const float*)d_in[12];
  const float* b_d   = (const float*)d_in[13];
  const int*   dst   = (const int*)d_in[15];
  float* out = (float*)d_out;

  char* ws = (char*)d_ws;
  // Timeline/aliasing:
  //   hbuf [0, 82.3MB): live conv1 -> enc, DEAD after enc.
  //   zT   [0, 32KB) + partial2 [64KB, 320KB): written AFTER enc (h dead).
  //   partial [off1, +41.2MB): live enc -> red1.
  //   TGbuf   [off1, +46.3MB): written by k_dectg (partial dead), read by att.
  float* hbuf = (float*)ws;
  float* zT   = (float*)ws;                               // 32 KB (dead-h zone)
  float* partial2 = (float*)(ws + (64<<10));              // 256 KB (dead-h zone)
  size_t off1 = (size_t)NBV*CH*sizeof(float);
  float* partial = (float*)(ws + off1);                   // 41.2 MB
  float* TGbuf   = (float*)(ws + off1);                   // 46.3 MB

  int grid_bv = (NBV + 255)/256;   // 1256

  k_conv1<<<grid_bv,256,0,stream>>>(x, aw, dst, u_e, c_e, W_e, b_e, hbuf);
  k_enc<<<NCHUNK,256,0,stream>>>(hbuf, W_enc, partial);
  dim3 gr1(32, RED_G);
  k_red1<<<gr1,256,0,stream>>>(partial, partial2);
  k_red2<<<32,256,0,stream>>>(partial2, b_enc, zT);
  int grid_dec = (KTOT + 255)/256;   // 1256
  k_dectg<<<grid_dec,256,0,stream>>>(zT, W_dec, b_dec, u_d, W_d, TGbuf);
  k_att<<<grid_bv,256,0,stream>>>(TGbuf, aw, dst, c_d, b_d, out);
}